// Round 2
// baseline (836.017 us; speedup 1.0000x reference)
//
#include <hip/hip_runtime.h>
#include <hip/hip_bf16.h>
#include <math.h>

// Problem constants (match reference)
#define Bn 8
#define Sn 4096
#define Dn 512
#define MODES 16
// 2*pi/4096
#define ANGF 0.0015339807878856412f

// ws layout (floats):
//   xs       : offset 0,          16,777,216  (B*S*D)
//   partials : offset 16,777,216,  8,388,608  (B*64 chunks*16 modes*512*2)
//   Y        : offset 25,165,824,    131,072  (B*16*512*2)
//   wT       : offset 25,296,896,    786,432  (3*512*512)
// total 26,083,328 floats = 104.3 MB
#define WS_XS_OFF 0
#define WS_PART_OFF 16777216
#define WS_Y_OFF 25165824
#define WS_WT_OFF 25296896

#define NCHUNK 64          // chunks along S for K1 partials
#define CH (Sn / NCHUNK)   // 64 rows per chunk

// ---------------------------------------------------------------------------
// K0: transpose conv_w (O,I,3) -> wT[t][d][o] for coalesced GEMM loads
// ---------------------------------------------------------------------------
__global__ __launch_bounds__(256) void k_transpose_w(
    const float* __restrict__ cw, float* __restrict__ wT) {
  int idx = blockIdx.x * 256 + threadIdx.x;  // 786432 total
  if (idx >= 3 * Dn * Dn) return;
  int o = idx & 511;
  int d = (idx >> 9) & 511;
  int t = idx >> 18;
  wT[idx] = cw[o * 1536 + d * 3 + t];
}

// ---------------------------------------------------------------------------
// K1: fused LayerNorm + 16-mode Fourier projection (partial sums per chunk)
// block = 256 threads, each handles 2 consecutive d. grid = B*NCHUNK.
// partials[(b*NCHUNK+c)*16+k][d] = (re, im) partial over chunk's 64 rows.
// ---------------------------------------------------------------------------
__global__ __launch_bounds__(256) void k_ln_project(
    const float* __restrict__ x, const float* __restrict__ gamma,
    const float* __restrict__ beta, float* __restrict__ partials) {
  int b = blockIdx.x / NCHUNK;
  int c = blockIdx.x % NCHUNK;
  int tid = threadIdx.x;
  int d0 = tid * 2;

  __shared__ float2 s_cs[MODES];
  __shared__ float2 s_red[4];

  float g0 = gamma[d0], g1 = gamma[d0 + 1];
  float be0 = beta[d0], be1 = beta[d0 + 1];

  float accRe0[MODES], accRe1[MODES], accIm0[MODES], accIm1[MODES];
#pragma unroll
  for (int k = 0; k < MODES; k++) {
    accRe0[k] = 0.f; accRe1[k] = 0.f; accIm0[k] = 0.f; accIm1[k] = 0.f;
  }

  int s_base = c * CH;
  for (int r = 0; r < CH; ++r) {
    int s = s_base + r;
    float2 xv = *(const float2*)&x[((size_t)(b * Sn + s)) * Dn + d0];
    float ps = xv.x + xv.y;
    float pq = xv.x * xv.x + xv.y * xv.y;
#pragma unroll
    for (int off = 32; off > 0; off >>= 1) {
      ps += __shfl_down(ps, off);
      pq += __shfl_down(pq, off);
    }
    if ((tid & 63) == 0) s_red[tid >> 6] = make_float2(ps, pq);
    if (tid < MODES) {
      int m = (tid * s) & (Sn - 1);
      float sn, cn;
      sincosf((float)m * ANGF, &sn, &cn);
      s_cs[tid] = make_float2(cn, sn);
    }
    __syncthreads();
    float sum = s_red[0].x + s_red[1].x + s_red[2].x + s_red[3].x;
    float sq = s_red[0].y + s_red[1].y + s_red[2].y + s_red[3].y;
    float mu = sum * (1.0f / Dn);
    float var = sq * (1.0f / Dn) - mu * mu;
    float rstd = rsqrtf(var + 1e-5f);
    float xn0 = (xv.x - mu) * rstd * g0 + be0;
    float xn1 = (xv.y - mu) * rstd * g1 + be1;
#pragma unroll
    for (int k = 0; k < MODES; k++) {
      float2 cs = s_cs[k];
      accRe0[k] += xn0 * cs.x;
      accRe1[k] += xn1 * cs.x;
      accIm0[k] -= xn0 * cs.y;   // X = sum xn * e^{-i theta}
      accIm1[k] -= xn1 * cs.y;
    }
    __syncthreads();
  }
  // write partials as float4 {re0,im0,re1,im1} covering (d0, d0+1)
  size_t base = ((size_t)(b * NCHUNK + c)) * MODES;
#pragma unroll
  for (int k = 0; k < MODES; k++) {
    float4 v = make_float4(accRe0[k], accIm0[k], accRe1[k], accIm1[k]);
    // float2 index (base+k)*Dn + d0  ==> float4 index ((base+k)*Dn + d0)/2
    *(float4*)&partials[(((base + k) * Dn) + (size_t)d0) * 2] = v;
  }
}

// ---------------------------------------------------------------------------
// K2: reduce partials over chunks, multiply by spectral weight, pre-scale.
// Combined ortho norm: (1/sqrt(S))*(1/sqrt(S)) = 1/4096, and the c2r
// Hermitian fold gives factor 2 for k>=1. Y[b][k][d] = (re,im).
// one thread per (b,k,d): 65536 threads.
// ---------------------------------------------------------------------------
__global__ __launch_bounds__(256) void k_reduce_modes(
    const float* __restrict__ partials, const float* __restrict__ wr,
    const float* __restrict__ wi, float* __restrict__ Y) {
  int idx = blockIdx.x * 256 + threadIdx.x;  // B*16*512 = 65536
  int d = idx & 511;
  int k = (idx >> 9) & 15;
  int b = idx >> 13;
  const float2* P = (const float2*)partials;
  float re = 0.f, im = 0.f;
  for (int c = 0; c < NCHUNK; c++) {
    float2 p = P[(((size_t)(b * NCHUNK + c)) * MODES + k) * Dn + d];
    re += p.x;
    im += p.y;
  }
  float wrv = wr[d * MODES + k];
  float wiv = wi[d * MODES + k];
  float yre = re * wrv - im * wiv;
  float yim = re * wiv + im * wrv;
  // BUGFIX R1: both rfft and irfft carry 1/sqrt(S)=1/64 under norm='ortho';
  // previous 1/64 & 2/64 was 64x too large (measured absmax 0.916 ~= 5.7
  // sigma of the predicted 64x-inflated xs distribution).
  float scale = (k == 0) ? (1.0f / 4096.0f) : (2.0f / 4096.0f);
  ((float2*)Y)[((size_t)b * MODES + k) * Dn + d] =
      make_float2(yre * scale, yim * scale);
}

// ---------------------------------------------------------------------------
// K3: synthesize xs[b,s,d] = sum_k ( Yre[k,d] cos - Yim[k,d] sin ), theta=2pi k s/S
// (Y pre-scaled; k=0 sin term is 0 so Im(Y0) is ignored, matching irfft c2r.)
// block = 256 threads (2 d each), 8 rows per block. grid = B*S/8 = 4096.
// ---------------------------------------------------------------------------
#define R3 8
__global__ __launch_bounds__(256) void k_synth(const float* __restrict__ Y,
                                               float* __restrict__ xs) {
  int blk = blockIdx.x;
  int b = blk / (Sn / R3);
  int s0 = (blk % (Sn / R3)) * R3;
  int tid = threadIdx.x;
  int d0 = tid * 2;

  __shared__ float2 s_cs[R3][MODES];
  if (tid < R3 * MODES) {
    int r = tid >> 4, k = tid & 15;
    int s = s0 + r;
    int m = (k * s) & (Sn - 1);
    float sn, cn;
    sincosf((float)m * ANGF, &sn, &cn);
    s_cs[r][k] = make_float2(cn, sn);
  }

  float yre0[MODES], yim0[MODES], yre1[MODES], yim1[MODES];
  const float4* Y4 = (const float4*)Y;
#pragma unroll
  for (int k = 0; k < MODES; k++) {
    // float2 index (b*16+k)*512 + d0 -> float4 index (b*16+k)*256 + tid
    float4 y = Y4[((size_t)b * MODES + k) * (Dn / 2) + tid];
    yre0[k] = y.x; yim0[k] = y.y; yre1[k] = y.z; yim1[k] = y.w;
  }
  __syncthreads();

  for (int r = 0; r < R3; r++) {
    float a0 = 0.f, a1 = 0.f;
#pragma unroll
    for (int k = 0; k < MODES; k++) {
      float2 cs = s_cs[r][k];
      a0 += yre0[k] * cs.x - yim0[k] * cs.y;
      a1 += yre1[k] * cs.x - yim1[k] * cs.y;
    }
    *(float2*)&xs[((size_t)(b * Sn + s0 + r)) * Dn + d0] = make_float2(a0, a1);
  }
}

// ---------------------------------------------------------------------------
// K4: conv as 3-tap shifted GEMM + fused epilogue out = xc + x + xs + conv_b.
// 128x128 tile per block, 8x8 per thread, K-chunks of 16 per tap.
// grid = (N/128, M/128) = (4, 256); M tiles never straddle a batch boundary.
// ---------------------------------------------------------------------------
#define BM 128
#define BN 128
#define BK 16
__global__ __launch_bounds__(256) void k_conv_gemm(
    const float* __restrict__ xs, const float* __restrict__ wT,
    const float* __restrict__ x, const float* __restrict__ conv_b,
    float* __restrict__ out) {
  __shared__ float As[BK][BM + 4];
  __shared__ float Ws[BK][BN + 4];

  int tid = threadIdx.x;
  int mt = blockIdx.y;  // 0..255
  int nt = blockIdx.x;  // 0..3
  int row0 = mt * BM;   // global row index (b*S + s)
  int col0 = nt * BN;
  int b = mt >> 5;              // S/BM = 32 tiles per batch
  int s0 = (mt & 31) * BM;      // local s base within batch

  int tr = tid >> 4, tc = tid & 15;

  float acc[8][8];
#pragma unroll
  for (int i = 0; i < 8; i++)
#pragma unroll
    for (int j = 0; j < 8; j++) acc[i][j] = 0.f;

  int am = tid >> 2;        // 0..63  (A row within tile, +64 for 2nd half)
  int ac = (tid & 3) * 4;   // 0,4,8,12 (A k within chunk)
  int wk = tid >> 4;        // 0..15  (W k within chunk)
  int wo = (tid & 15) * 4;  // 0..60  (W col, +64 for 2nd half)

  for (int t = 0; t < 3; ++t) {
    for (int kc = 0; kc < Dn; kc += BK) {
#pragma unroll
      for (int half = 0; half < 2; ++half) {
        int m = am + half * 64;
        int s = s0 + m + t - 1;
        float4 v = make_float4(0.f, 0.f, 0.f, 0.f);
        if (s >= 0 && s < Sn)
          v = *(const float4*)&xs[((size_t)(b * Sn + s)) * Dn + kc + ac];
        As[ac + 0][m] = v.x;
        As[ac + 1][m] = v.y;
        As[ac + 2][m] = v.z;
        As[ac + 3][m] = v.w;
      }
#pragma unroll
      for (int half = 0; half < 2; ++half) {
        int o = wo + half * 64;
        float4 v = *(const float4*)&wT[((size_t)(t * Dn + kc + wk)) * Dn +
                                       col0 + o];
        *(float4*)&Ws[wk][o] = v;
      }
      __syncthreads();
#pragma unroll
      for (int kk = 0; kk < BK; ++kk) {
        float a[8], w[8];
        *(float4*)&a[0] = *(const float4*)&As[kk][tr * 8];
        *(float4*)&a[4] = *(const float4*)&As[kk][tr * 8 + 4];
        *(float4*)&w[0] = *(const float4*)&Ws[kk][tc * 8];
        *(float4*)&w[4] = *(const float4*)&Ws[kk][tc * 8 + 4];
#pragma unroll
        for (int i = 0; i < 8; i++)
#pragma unroll
          for (int j = 0; j < 8; j++) acc[i][j] += a[i] * w[j];
      }
      __syncthreads();
    }
  }

  // epilogue: out = acc + x + xs + conv_b
  float cb[8];
#pragma unroll
  for (int j = 0; j < 8; j++) cb[j] = conv_b[col0 + tc * 8 + j];
#pragma unroll
  for (int i = 0; i < 8; i++) {
    size_t r = (size_t)row0 + tr * 8 + i;
    size_t base = r * Dn + col0 + tc * 8;
#pragma unroll
    for (int j4 = 0; j4 < 2; j4++) {
      float4 xv = *(const float4*)&x[base + j4 * 4];
      float4 sv = *(const float4*)&xs[base + j4 * 4];
      float4 o;
      o.x = acc[i][j4 * 4 + 0] + xv.x + sv.x + cb[j4 * 4 + 0];
      o.y = acc[i][j4 * 4 + 1] + xv.y + sv.y + cb[j4 * 4 + 1];
      o.z = acc[i][j4 * 4 + 2] + xv.z + sv.z + cb[j4 * 4 + 2];
      o.w = acc[i][j4 * 4 + 3] + xv.w + sv.w + cb[j4 * 4 + 3];
      *(float4*)&out[base + j4 * 4] = o;
    }
  }
}

// ---------------------------------------------------------------------------
extern "C" void kernel_launch(void* const* d_in, const int* in_sizes, int n_in,
                              void* d_out, int out_size, void* d_ws,
                              size_t ws_size, hipStream_t stream) {
  const float* x = (const float*)d_in[0];
  const float* gamma = (const float*)d_in[1];
  const float* beta = (const float*)d_in[2];
  const float* wr = (const float*)d_in[3];
  const float* wi = (const float*)d_in[4];
  const float* conv_w = (const float*)d_in[5];
  const float* conv_b = (const float*)d_in[6];
  float* out = (float*)d_out;

  float* ws = (float*)d_ws;
  float* xs = ws + WS_XS_OFF;
  float* partials = ws + WS_PART_OFF;
  float* Y = ws + WS_Y_OFF;
  float* wT = ws + WS_WT_OFF;

  // K0: weight transpose (3*512*512 / 256 = 3072 blocks)
  hipLaunchKernelGGL(k_transpose_w, dim3(3072), dim3(256), 0, stream, conv_w,
                     wT);
  // K1: LN + projection (B*NCHUNK = 512 blocks)
  hipLaunchKernelGGL(k_ln_project, dim3(Bn * NCHUNK), dim3(256), 0, stream, x,
                     gamma, beta, partials);
  // K2: mode reduce (65536 / 256 = 256 blocks)
  hipLaunchKernelGGL(k_reduce_modes, dim3(256), dim3(256), 0, stream, partials,
                     wr, wi, Y);
  // K3: synthesis (B*S/8 = 4096 blocks)
  hipLaunchKernelGGL(k_synth, dim3(Bn * Sn / R3), dim3(256), 0, stream, Y, xs);
  // K4: conv GEMM + epilogue (grid 4 x 256)
  hipLaunchKernelGGL(k_conv_gemm, dim3(4, 256), dim3(256), 0, stream, xs, wT, x,
                     conv_b, out);
}

// Round 3
// 265.230 us; speedup vs baseline: 3.1520x; 3.1520x over previous
//
#include <hip/hip_runtime.h>
#include <hip/hip_bf16.h>
#include <math.h>

// Problem constants
#define Bn 8
#define Sn 4096
#define Dn 512
#define MODES 16
#define ANGF 0.0015339807878856412f  // 2*pi/4096
#define NCHUNK 64

typedef __attribute__((ext_vector_type(8))) short short8;
typedef __attribute__((ext_vector_type(4))) float f32x4;

// ws layout:
//   xs_swz  : bf16 [B][4098][512]  (rows sp=0 and sp=4097 are zero pads;
//             16B-chunk index XOR-swizzled by (sp&7))       33,570,816 B
//   partials: fp32 [B*64][16][512][2]                       33,554,432 B
//   Y       : fp32 [B][16][512][2]                             524,288 B
//   wTb     : bf16 [3][512][512]  (chunk-swizzled by (o&7),
//             center tap has +I folded in)                   1,572,864 B
#define XS_BYTES (Bn * 4098 * Dn * 2)
#define PART_OFF_F (XS_BYTES / 4)
#define PART_FLOATS (Bn * 64 * MODES * Dn * 2)
#define Y_OFF_F (PART_OFF_F + PART_FLOATS)
#define Y_FLOATS (Bn * MODES * Dn * 2)
#define WTB_OFF_H ((Y_OFF_F + Y_FLOATS) * 2)

__device__ __forceinline__ void gld_lds16(const void* g, void* l) {
  __builtin_amdgcn_global_load_lds(
      (const __attribute__((address_space(1))) unsigned int*)g,
      (__attribute__((address_space(3))) unsigned int*)l, 16, 0, 0);
}

// ---------------------------------------------------------------------------
// K0: build bf16 B operand wTb[t][o][k], chunk-swizzled by (o&7), with the
// identity folded into the center tap: w'[o][d][1] += (o==d). This makes the
// GEMM compute conv(xs) + xs, removing the xs term from K4's epilogue.
// ---------------------------------------------------------------------------
__global__ __launch_bounds__(256) void k_build_w(
    const float* __restrict__ cw, unsigned short* __restrict__ wTb) {
  int idx = blockIdx.x * 256 + threadIdx.x;  // 786432
  int e = idx & 7;
  int c = (idx >> 3) & 63;
  int o = (idx >> 9) & 511;
  int t = idx >> 18;
  int d = ((c ^ (o & 7)) << 3) + e;  // de-swizzle: logical input channel
  float v = cw[o * 1536 + d * 3 + t];
  if (t == 1 && o == d) v += 1.0f;
  ((__hip_bfloat16*)wTb)[idx] = __float2bfloat16(v);
}

// ---------------------------------------------------------------------------
// K0b: zero the halo pad rows of xs_swz (sp=0 and sp=4097 per batch).
// ---------------------------------------------------------------------------
__global__ __launch_bounds__(256) void k_zero_pads(
    unsigned short* __restrict__ xs_swz) {
  int idx = blockIdx.x * 256 + threadIdx.x;  // 8192
  int b = idx >> 10;
  int r = (idx >> 9) & 1;
  int d = idx & 511;
  int sp = r ? 4097 : 0;
  xs_swz[(((size_t)(b * 4098 + sp)) << 9) + d] = 0;
}

// ---------------------------------------------------------------------------
// K1: fused LayerNorm + 16-mode DFT projection. Restructured vs R1: one
// barrier per 64-row chunk instead of two per row. Phase 1: each wave
// computes mean/rstd for 16 rows (coalesced float4 + shuffle reduce).
// Phase 2: barrier-free accumulation with a precomputed twiddle table.
// ---------------------------------------------------------------------------
__global__ __launch_bounds__(256) void k_ln_project(
    const float* __restrict__ x, const float* __restrict__ gamma,
    const float* __restrict__ beta, float* __restrict__ partials) {
  int b = blockIdx.x / NCHUNK;
  int c = blockIdx.x % NCHUNK;
  int tid = threadIdx.x;
  int lane = tid & 63, wave = tid >> 6;
  int s_base = c * 64;

  __shared__ float2 s_tw[64 * MODES];  // [row][mode] = (cos, sin)
  __shared__ float2 s_mv[64];          // (mu, rstd)

#pragma unroll
  for (int u = 0; u < 4; u++) {
    int idx = tid * 4 + u;  // 1024
    int r = idx >> 4, k = idx & 15;
    int m = ((s_base + r) * k) & (Sn - 1);
    float sn, cn;
    sincosf((float)m * ANGF, &sn, &cn);
    s_tw[idx] = make_float2(cn, sn);
  }

  // phase 1: per-row mean / rstd (wave w handles rows w*16 .. w*16+15)
  for (int j = 0; j < 16; j++) {
    int r = wave * 16 + j;
    const float4* px = (const float4*)&x[((size_t)(b * Sn + s_base + r)) << 9];
    float4 v0 = px[lane * 2];
    float4 v1 = px[lane * 2 + 1];
    float ps = v0.x + v0.y + v0.z + v0.w + v1.x + v1.y + v1.z + v1.w;
    float pq = v0.x * v0.x + v0.y * v0.y + v0.z * v0.z + v0.w * v0.w +
               v1.x * v1.x + v1.y * v1.y + v1.z * v1.z + v1.w * v1.w;
#pragma unroll
    for (int off = 32; off > 0; off >>= 1) {
      ps += __shfl_down(ps, off);
      pq += __shfl_down(pq, off);
    }
    if (lane == 0) {
      float mu = ps * (1.0f / Dn);
      float var = pq * (1.0f / Dn) - mu * mu;
      s_mv[r] = make_float2(mu, rsqrtf(var + 1e-5f));
    }
  }
  __syncthreads();

  // phase 2: accumulate 16-mode projection, 2 d per thread, no barriers
  int d0 = tid * 2;
  float g0 = gamma[d0], g1 = gamma[d0 + 1];
  float be0 = beta[d0], be1 = beta[d0 + 1];
  float accRe0[MODES], accRe1[MODES], accIm0[MODES], accIm1[MODES];
#pragma unroll
  for (int k = 0; k < MODES; k++) {
    accRe0[k] = 0.f; accRe1[k] = 0.f; accIm0[k] = 0.f; accIm1[k] = 0.f;
  }
  for (int r = 0; r < 64; ++r) {
    float2 xv = *(const float2*)&x[(((size_t)(b * Sn + s_base + r)) << 9) + d0];
    float2 mv = s_mv[r];
    float xn0 = (xv.x - mv.x) * mv.y * g0 + be0;
    float xn1 = (xv.y - mv.x) * mv.y * g1 + be1;
    const float2* tw = &s_tw[r * MODES];
#pragma unroll
    for (int k = 0; k < MODES; k++) {
      float2 cs = tw[k];
      accRe0[k] += xn0 * cs.x;
      accRe1[k] += xn1 * cs.x;
      accIm0[k] -= xn0 * cs.y;
      accIm1[k] -= xn1 * cs.y;
    }
  }
  size_t base = ((size_t)(b * NCHUNK + c)) * MODES;
#pragma unroll
  for (int k = 0; k < MODES; k++) {
    float4 v = make_float4(accRe0[k], accIm0[k], accRe1[k], accIm1[k]);
    *(float4*)&partials[(((base + k) * Dn) + (size_t)d0) * 2] = v;
  }
}

// ---------------------------------------------------------------------------
// K2: reduce partials over chunks, apply spectral weight, fold ortho norms
// (1/4096; 2/4096 for k>=1 Hermitian fold).
// ---------------------------------------------------------------------------
__global__ __launch_bounds__(256) void k_reduce_modes(
    const float* __restrict__ partials, const float* __restrict__ wr,
    const float* __restrict__ wi, float* __restrict__ Y) {
  int idx = blockIdx.x * 256 + threadIdx.x;  // 65536
  int d = idx & 511;
  int k = (idx >> 9) & 15;
  int b = idx >> 13;
  const float2* P = (const float2*)partials;
  float re = 0.f, im = 0.f;
  for (int c = 0; c < NCHUNK; c++) {
    float2 p = P[(((size_t)(b * NCHUNK + c)) * MODES + k) * Dn + d];
    re += p.x;
    im += p.y;
  }
  float wrv = wr[d * MODES + k];
  float wiv = wi[d * MODES + k];
  float yre = re * wrv - im * wiv;
  float yim = re * wiv + im * wrv;
  float scale = (k == 0) ? (1.0f / 4096.0f) : (2.0f / 4096.0f);
  ((float2*)Y)[((size_t)b * MODES + k) * Dn + d] =
      make_float2(yre * scale, yim * scale);
}

// ---------------------------------------------------------------------------
// K3: synthesize xs and store as bf16 into the swizzled, padded layout.
// xs[b,s,d] = sum_k (Yre cos - Yim sin). Row sp = s+1; 16B-chunk (8 halves)
// index is XORed with (sp&7) so K4's MFMA fragment reads are conflict-free.
// ---------------------------------------------------------------------------
#define R3 8
__global__ __launch_bounds__(256) void k_synth(
    const float* __restrict__ Y, unsigned short* __restrict__ xs_swz) {
  int blk = blockIdx.x;
  int b = blk / (Sn / R3);
  int s0 = (blk % (Sn / R3)) * R3;
  int tid = threadIdx.x;
  int d0 = tid * 2;

  __shared__ float2 s_cs[R3][MODES];
  if (tid < R3 * MODES) {
    int r = tid >> 4, k = tid & 15;
    int m = (k * (s0 + r)) & (Sn - 1);
    float sn, cn;
    sincosf((float)m * ANGF, &sn, &cn);
    s_cs[r][k] = make_float2(cn, sn);
  }

  float yre0[MODES], yim0[MODES], yre1[MODES], yim1[MODES];
  const float4* Y4 = (const float4*)Y;
#pragma unroll
  for (int k = 0; k < MODES; k++) {
    float4 y = Y4[((size_t)b * MODES + k) * (Dn / 2) + tid];
    yre0[k] = y.x; yim0[k] = y.y; yre1[k] = y.z; yim1[k] = y.w;
  }
  __syncthreads();

  for (int r = 0; r < R3; r++) {
    float a0 = 0.f, a1 = 0.f;
#pragma unroll
    for (int k = 0; k < MODES; k++) {
      float2 cs = s_cs[r][k];
      a0 += yre0[k] * cs.x - yim0[k] * cs.y;
      a1 += yre1[k] * cs.x - yim1[k] * cs.y;
    }
    int sp = s0 + r + 1;
    int cc = (d0 >> 3) ^ (sp & 7);
    size_t half = (((size_t)(b * 4098 + sp)) << 9) + (cc << 3) + (d0 & 7);
    __hip_bfloat162 h;
    h.x = __float2bfloat16(a0);
    h.y = __float2bfloat16(a1);
    *(__hip_bfloat162*)&xs_swz[half] = h;
  }
}

// ---------------------------------------------------------------------------
// K4: bf16 MFMA conv-GEMM. out = x + sum_t xs[s+t-1] @ w'[t] + conv_b
// (the +xs residual is folded into w'[1]). Block 128x128, 4 waves 2x2,
// wave tile 64x64 = 4x4 of 16x16x32 MFMAs, BK=64 halves, 24 K-iters.
// A and B staged via global_load_lds width-16; swizzled layouts make the
// ds_read_b128 fragment reads 2-way-max (free) bank patterns.
// ---------------------------------------------------------------------------
__global__ __launch_bounds__(256) void k_conv_gemm(
    const unsigned short* __restrict__ xs_swz,
    const unsigned short* __restrict__ wTb, const float* __restrict__ x,
    const float* __restrict__ conv_b, float* __restrict__ out) {
  __shared__ unsigned short As[128 * 64];  // [m][chunk-swizzled k] 16 KB
  __shared__ unsigned short Bs[128 * 64];  // [n][chunk-swizzled k] 16 KB

  int tid = threadIdx.x;
  int lane = tid & 63, wave = tid >> 6;
  int wm = wave >> 1, wn = wave & 1;
  int q = lane >> 4, r15 = lane & 15;

  int mt = blockIdx.y;         // 0..255
  int col0 = blockIdx.x * 128; // 0..384
  int bidx = mt >> 5;
  int sbase = (mt & 31) * 128; // batch-local s of m=0 (storage row sp=sbase+t+m)
  int row0 = mt * 128;

  f32x4 acc[4][4];
#pragma unroll
  for (int i = 0; i < 4; i++)
#pragma unroll
    for (int j = 0; j < 4; j++) acc[i][j] = (f32x4){0.f, 0.f, 0.f, 0.f};

  int lrow = lane >> 3;        // 0..7 row within an 8-row staging issue
  int lchunk = lane & 7;       // 16B chunk within a 64-half row slice
  bool first = true;

  for (int t = 0; t < 3; ++t) {
    int akey = (r15 + t) & 7;  // A swizzle key = (sp&7) = (m+t)&7
    for (int c8 = 0; c8 < 8; ++c8) {
      int kc = c8 * 64;
      if (!first) __syncthreads();  // protect LDS from overwrite
      first = false;
      // stage: each wave issues 4 A-rows-of-8 and 4 B-rows-of-8 (16B/lane)
#pragma unroll
      for (int ii = 0; ii < 4; ++ii) {
        int i = wave * 4 + ii;
        int m = i * 8 + lrow;
        int sp = sbase + t + m;
        const unsigned short* gA = xs_swz +
            (((size_t)(bidx * 4098 + sp)) << 9) + kc + (lchunk << 3);
        gld_lds16(gA, (void*)(As + i * 512 + (lane << 3)));
        const unsigned short* gB = wTb + (((size_t)t) << 18) +
            (((size_t)(col0 + m)) << 9) + kc + (lchunk << 3);
        gld_lds16(gB, (void*)(Bs + i * 512 + (lane << 3)));
      }
      __syncthreads();  // drains vmcnt(0): LDS tiles ready
#pragma unroll
      for (int kstep = 0; kstep < 2; ++kstep) {
        int q4 = kstep * 4 + q;
        short8 av[4], bv[4];
#pragma unroll
        for (int mf = 0; mf < 4; ++mf)
          av[mf] = *(const short8*)&As[(wm * 64 + mf * 16 + r15) * 64 +
                                       ((q4 ^ akey) << 3)];
#pragma unroll
        for (int nf = 0; nf < 4; ++nf)
          bv[nf] = *(const short8*)&Bs[(wn * 64 + nf * 16 + r15) * 64 +
                                       ((q4 ^ (r15 & 7)) << 3)];
#pragma unroll
        for (int mf = 0; mf < 4; ++mf)
#pragma unroll
          for (int nf = 0; nf < 4; ++nf)
            acc[mf][nf] = __builtin_amdgcn_mfma_f32_16x16x32_bf16(
                av[mf], bv[nf], acc[mf][nf], 0, 0, 0);
      }
    }
  }

  // epilogue: out = acc + x + conv_b   (C/D: col=lane&15, row=quad*4+reg)
  float cb[4];
#pragma unroll
  for (int nf = 0; nf < 4; ++nf)
    cb[nf] = conv_b[col0 + wn * 64 + nf * 16 + r15];
#pragma unroll
  for (int mf = 0; mf < 4; ++mf) {
#pragma unroll
    for (int rr = 0; rr < 4; ++rr) {
      int grow = row0 + wm * 64 + mf * 16 + q * 4 + rr;
      size_t base = ((size_t)grow << 9) + col0 + wn * 64 + r15;
#pragma unroll
      for (int nf = 0; nf < 4; ++nf)
        out[base + nf * 16] = acc[mf][nf][rr] + x[base + nf * 16] + cb[nf];
    }
  }
}

// ---------------------------------------------------------------------------
extern "C" void kernel_launch(void* const* d_in, const int* in_sizes, int n_in,
                              void* d_out, int out_size, void* d_ws,
                              size_t ws_size, hipStream_t stream) {
  const float* x = (const float*)d_in[0];
  const float* gamma = (const float*)d_in[1];
  const float* beta = (const float*)d_in[2];
  const float* wr = (const float*)d_in[3];
  const float* wi = (const float*)d_in[4];
  const float* conv_w = (const float*)d_in[5];
  const float* conv_b = (const float*)d_in[6];
  float* out = (float*)d_out;

  unsigned short* xs_swz = (unsigned short*)d_ws;
  float* partials = (float*)d_ws + PART_OFF_F;
  float* Y = (float*)d_ws + Y_OFF_F;
  unsigned short* wTb = (unsigned short*)d_ws + WTB_OFF_H;

  hipLaunchKernelGGL(k_build_w, dim3(3072), dim3(256), 0, stream, conv_w, wTb);
  hipLaunchKernelGGL(k_zero_pads, dim3(32), dim3(256), 0, stream, xs_swz);
  hipLaunchKernelGGL(k_ln_project, dim3(Bn * NCHUNK), dim3(256), 0, stream, x,
                     gamma, beta, partials);
  hipLaunchKernelGGL(k_reduce_modes, dim3(256), dim3(256), 0, stream, partials,
                     wr, wi, Y);
  hipLaunchKernelGGL(k_synth, dim3(Bn * Sn / R3), dim3(256), 0, stream, Y,
                     xs_swz);
  hipLaunchKernelGGL(k_conv_gemm, dim3(4, 256), dim3(256), 0, stream, xs_swz,
                     wTb, x, conv_b, out);
}

// Round 4
// 252.211 us; speedup vs baseline: 3.3148x; 1.0516x over previous
//
#include <hip/hip_runtime.h>
#include <hip/hip_bf16.h>
#include <math.h>

// Problem constants
#define Bn 8
#define Sn 4096
#define Dn 512
#define MODES 16
#define ANGF 0.0015339807878856412f  // 2*pi/4096
#define NCHUNK 64

typedef __attribute__((ext_vector_type(8))) short short8;
typedef __attribute__((ext_vector_type(4))) float f32x4;

// ws layout:
//   xs_swz  : bf16 [B][4098][512]  (rows sp=0 and sp=4097 are zero pads;
//             16B-chunk index XOR-swizzled by (sp&7))       33,570,816 B
//   partials: fp32 [B*64][16][512][2]                       33,554,432 B
//   Y       : fp32 [B][16][512][2]                             524,288 B
//   wTb     : bf16 [3][512][512]  (chunk-swizzled by (o&7),
//             center tap has +I folded in)                   1,572,864 B
#define XS_BYTES (Bn * 4098 * Dn * 2)
#define PART_OFF_F (XS_BYTES / 4)
#define PART_FLOATS (Bn * 64 * MODES * Dn * 2)
#define Y_OFF_F (PART_OFF_F + PART_FLOATS)
#define Y_FLOATS (Bn * MODES * Dn * 2)
#define WTB_OFF_H ((Y_OFF_F + Y_FLOATS) * 2)

__device__ __forceinline__ void gld_lds16(const void* g, void* l) {
  __builtin_amdgcn_global_load_lds(
      (const __attribute__((address_space(1))) unsigned int*)g,
      (__attribute__((address_space(3))) unsigned int*)l, 16, 0, 0);
}

// ---------------------------------------------------------------------------
// K0: build bf16 B operand wTb[t][o][k], chunk-swizzled by (o&7), with the
// identity folded into the center tap: w'[o][d][1] += (o==d). Tail blocks
// zero the xs halo pad rows (sp=0, sp=4097 per batch).
// ---------------------------------------------------------------------------
__global__ __launch_bounds__(256) void k_build_w(
    const float* __restrict__ cw, unsigned short* __restrict__ wTb,
    unsigned short* __restrict__ xs_swz) {
  int idx = blockIdx.x * 256 + threadIdx.x;  // 786432 + 8192
  if (idx < 786432) {
    int e = idx & 7;
    int c = (idx >> 3) & 63;
    int o = (idx >> 9) & 511;
    int t = idx >> 18;
    int d = ((c ^ (o & 7)) << 3) + e;  // de-swizzle: logical input channel
    float v = cw[o * 1536 + d * 3 + t];
    if (t == 1 && o == d) v += 1.0f;
    ((__hip_bfloat16*)wTb)[idx] = __float2bfloat16(v);
  } else {
    int i2 = idx - 786432;  // 8192 pad halves
    int b = i2 >> 10;
    int r = (i2 >> 9) & 1;
    int d = i2 & 511;
    int sp = r ? 4097 : 0;
    xs_swz[(((size_t)(b * 4098 + sp)) << 9) + d] = 0;
  }
}

// ---------------------------------------------------------------------------
// K1: fused LayerNorm + 16-mode DFT projection. Phase 1: per-row mean/rstd
// (one wave per 16 rows). Phase 2: barrier-free accumulation with a
// precomputed twiddle table; partials per 64-row chunk.
// ---------------------------------------------------------------------------
__global__ __launch_bounds__(256) void k_ln_project(
    const float* __restrict__ x, const float* __restrict__ gamma,
    const float* __restrict__ beta, float* __restrict__ partials) {
  int b = blockIdx.x / NCHUNK;
  int c = blockIdx.x % NCHUNK;
  int tid = threadIdx.x;
  int lane = tid & 63, wave = tid >> 6;
  int s_base = c * 64;

  __shared__ float2 s_tw[64 * MODES];  // [row][mode] = (cos, sin)
  __shared__ float2 s_mv[64];          // (mu, rstd)

#pragma unroll
  for (int u = 0; u < 4; u++) {
    int idx = tid * 4 + u;  // 1024
    int r = idx >> 4, k = idx & 15;
    int m = ((s_base + r) * k) & (Sn - 1);
    float sn, cn;
    sincosf((float)m * ANGF, &sn, &cn);
    s_tw[idx] = make_float2(cn, sn);
  }

  // phase 1: per-row mean / rstd (wave w handles rows w*16 .. w*16+15)
  for (int j = 0; j < 16; j++) {
    int r = wave * 16 + j;
    const float4* px = (const float4*)&x[((size_t)(b * Sn + s_base + r)) << 9];
    float4 v0 = px[lane * 2];
    float4 v1 = px[lane * 2 + 1];
    float ps = v0.x + v0.y + v0.z + v0.w + v1.x + v1.y + v1.z + v1.w;
    float pq = v0.x * v0.x + v0.y * v0.y + v0.z * v0.z + v0.w * v0.w +
               v1.x * v1.x + v1.y * v1.y + v1.z * v1.z + v1.w * v1.w;
#pragma unroll
    for (int off = 32; off > 0; off >>= 1) {
      ps += __shfl_down(ps, off);
      pq += __shfl_down(pq, off);
    }
    if (lane == 0) {
      float mu = ps * (1.0f / Dn);
      float var = pq * (1.0f / Dn) - mu * mu;
      s_mv[r] = make_float2(mu, rsqrtf(var + 1e-5f));
    }
  }
  __syncthreads();

  // phase 2: accumulate 16-mode projection, 2 d per thread, no barriers
  int d0 = tid * 2;
  float g0 = gamma[d0], g1 = gamma[d0 + 1];
  float be0 = beta[d0], be1 = beta[d0 + 1];
  float accRe0[MODES], accRe1[MODES], accIm0[MODES], accIm1[MODES];
#pragma unroll
  for (int k = 0; k < MODES; k++) {
    accRe0[k] = 0.f; accRe1[k] = 0.f; accIm0[k] = 0.f; accIm1[k] = 0.f;
  }
  for (int r = 0; r < 64; ++r) {
    float2 xv = *(const float2*)&x[(((size_t)(b * Sn + s_base + r)) << 9) + d0];
    float2 mv = s_mv[r];
    float xn0 = (xv.x - mv.x) * mv.y * g0 + be0;
    float xn1 = (xv.y - mv.x) * mv.y * g1 + be1;
    const float2* tw = &s_tw[r * MODES];
#pragma unroll
    for (int k = 0; k < MODES; k++) {
      float2 cs = tw[k];
      accRe0[k] += xn0 * cs.x;
      accRe1[k] += xn1 * cs.x;
      accIm0[k] -= xn0 * cs.y;
      accIm1[k] -= xn1 * cs.y;
    }
  }
  size_t base = ((size_t)(b * NCHUNK + c)) * MODES;
#pragma unroll
  for (int k = 0; k < MODES; k++) {
    float4 v = make_float4(accRe0[k], accIm0[k], accRe1[k], accIm1[k]);
    *(float4*)&partials[(((base + k) * Dn) + (size_t)d0) * 2] = v;
  }
}

// ---------------------------------------------------------------------------
// K2: reduce partials over chunks, apply spectral weight, fold ortho norms
// (1/4096; 2/4096 for k>=1 Hermitian fold). Unroll 8 => 8 outstanding loads
// (was latency-bound at ~1 outstanding).
// ---------------------------------------------------------------------------
__global__ __launch_bounds__(256) void k_reduce_modes(
    const float* __restrict__ partials, const float* __restrict__ wr,
    const float* __restrict__ wi, float* __restrict__ Y) {
  int idx = blockIdx.x * 256 + threadIdx.x;  // 65536
  int d = idx & 511;
  int k = (idx >> 9) & 15;
  int b = idx >> 13;
  const float2* P = (const float2*)partials;
  float re = 0.f, im = 0.f;
#pragma unroll 8
  for (int c = 0; c < NCHUNK; c++) {
    float2 p = P[(((size_t)(b * NCHUNK + c)) * MODES + k) * Dn + d];
    re += p.x;
    im += p.y;
  }
  float wrv = wr[d * MODES + k];
  float wiv = wi[d * MODES + k];
  float yre = re * wrv - im * wiv;
  float yim = re * wiv + im * wrv;
  float scale = (k == 0) ? (1.0f / 4096.0f) : (2.0f / 4096.0f);
  ((float2*)Y)[((size_t)b * MODES + k) * Dn + d] =
      make_float2(yre * scale, yim * scale);
}

// ---------------------------------------------------------------------------
// K3: synthesize xs and store as bf16 into the swizzled, padded layout.
// xs[b,s,d] = sum_k (Yre cos - Yim sin). Row sp = s+1; 16B-chunk (8 halves)
// index is XORed with (sp&7) so K4's MFMA fragment reads are conflict-free.
// ---------------------------------------------------------------------------
#define R3 8
__global__ __launch_bounds__(256) void k_synth(
    const float* __restrict__ Y, unsigned short* __restrict__ xs_swz) {
  int blk = blockIdx.x;
  int b = blk / (Sn / R3);
  int s0 = (blk % (Sn / R3)) * R3;
  int tid = threadIdx.x;
  int d0 = tid * 2;

  __shared__ float2 s_cs[R3][MODES];
  if (tid < R3 * MODES) {
    int r = tid >> 4, k = tid & 15;
    int m = (k * (s0 + r)) & (Sn - 1);
    float sn, cn;
    sincosf((float)m * ANGF, &sn, &cn);
    s_cs[r][k] = make_float2(cn, sn);
  }

  float yre0[MODES], yim0[MODES], yre1[MODES], yim1[MODES];
  const float4* Y4 = (const float4*)Y;
#pragma unroll
  for (int k = 0; k < MODES; k++) {
    float4 y = Y4[((size_t)b * MODES + k) * (Dn / 2) + tid];
    yre0[k] = y.x; yim0[k] = y.y; yre1[k] = y.z; yim1[k] = y.w;
  }
  __syncthreads();

  for (int r = 0; r < R3; r++) {
    float a0 = 0.f, a1 = 0.f;
#pragma unroll
    for (int k = 0; k < MODES; k++) {
      float2 cs = s_cs[r][k];
      a0 += yre0[k] * cs.x - yim0[k] * cs.y;
      a1 += yre1[k] * cs.x - yim1[k] * cs.y;
    }
    int sp = s0 + r + 1;
    int cc = (d0 >> 3) ^ (sp & 7);
    size_t half = (((size_t)(b * 4098 + sp)) << 9) + (cc << 3) + (d0 & 7);
    __hip_bfloat162 h;
    h.x = __float2bfloat16(a0);
    h.y = __float2bfloat16(a1);
    *(__hip_bfloat162*)&xs_swz[half] = h;
  }
}

// ---------------------------------------------------------------------------
// K4: bf16 MFMA conv-GEMM. out = x + sum_t xs[s+t-1] @ w'[t] + conv_b
// (the +xs residual is folded into w'[1]). Block 128x128, 4 waves 2x2,
// wave tile 64x64 = 4x4 of 16x16x32 MFMAs, BK=64 halves, 24 K-iters.
// XCD-aware swizzle (R4): linear grid 1024; id&7 selects XCD (round-robin
// dispatch heuristic), so all 4 column-blocks of an mt share one XCD's L2
// and each XCD owns a contiguous 32-mt A range (~4.3 MB ~= its L2).
// Prev round: 4 nt-blocks landed on 4 XCDs -> A fetched 4x (232 MB FETCH).
// ---------------------------------------------------------------------------
__global__ __launch_bounds__(256) void k_conv_gemm(
    const unsigned short* __restrict__ xs_swz,
    const unsigned short* __restrict__ wTb, const float* __restrict__ x,
    const float* __restrict__ conv_b, float* __restrict__ out) {
  __shared__ unsigned short As[128 * 64];  // [m][chunk-swizzled k] 16 KB
  __shared__ unsigned short Bs[128 * 64];  // [n][chunk-swizzled k] 16 KB

  int tid = threadIdx.x;
  int lane = tid & 63, wave = tid >> 6;
  int wm = wave >> 1, wn = wave & 1;
  int q = lane >> 4, r15 = lane & 15;

  int id = blockIdx.x;           // 0..1023
  int xcd = id & 7;
  int slot = id >> 3;            // 0..127
  int mt = xcd * 32 + (slot >> 2);
  int nt = slot & 3;
  int col0 = nt * 128;
  int bidx = mt >> 5;
  int sbase = (mt & 31) * 128;   // batch-local s of m=0 (storage sp=sbase+t+m)
  int row0 = mt * 128;

  f32x4 acc[4][4];
#pragma unroll
  for (int i = 0; i < 4; i++)
#pragma unroll
    for (int j = 0; j < 4; j++) acc[i][j] = (f32x4){0.f, 0.f, 0.f, 0.f};

  int lrow = lane >> 3;        // 0..7 row within an 8-row staging issue
  int lchunk = lane & 7;       // 16B chunk within a 64-half row slice
  bool first = true;

  for (int t = 0; t < 3; ++t) {
    int akey = (r15 + t) & 7;  // A swizzle key = (sp&7) = (m+t)&7
    for (int c8 = 0; c8 < 8; ++c8) {
      int kc = c8 * 64;
      if (!first) __syncthreads();  // protect LDS from overwrite
      first = false;
      // stage: each wave issues 4 A-rows-of-8 and 4 B-rows-of-8 (16B/lane)
#pragma unroll
      for (int ii = 0; ii < 4; ++ii) {
        int i = wave * 4 + ii;
        int m = i * 8 + lrow;
        int sp = sbase + t + m;
        const unsigned short* gA = xs_swz +
            (((size_t)(bidx * 4098 + sp)) << 9) + kc + (lchunk << 3);
        gld_lds16(gA, (void*)(As + i * 512 + (lane << 3)));
        const unsigned short* gB = wTb + (((size_t)t) << 18) +
            (((size_t)(col0 + m)) << 9) + kc + (lchunk << 3);
        gld_lds16(gB, (void*)(Bs + i * 512 + (lane << 3)));
      }
      __syncthreads();  // drains vmcnt(0): LDS tiles ready
#pragma unroll
      for (int kstep = 0; kstep < 2; ++kstep) {
        int q4 = kstep * 4 + q;
        short8 av[4], bv[4];
#pragma unroll
        for (int mf = 0; mf < 4; ++mf)
          av[mf] = *(const short8*)&As[(wm * 64 + mf * 16 + r15) * 64 +
                                       ((q4 ^ akey) << 3)];
#pragma unroll
        for (int nf = 0; nf < 4; ++nf)
          bv[nf] = *(const short8*)&Bs[(wn * 64 + nf * 16 + r15) * 64 +
                                       ((q4 ^ (r15 & 7)) << 3)];
#pragma unroll
        for (int mf = 0; mf < 4; ++mf)
#pragma unroll
          for (int nf = 0; nf < 4; ++nf)
            acc[mf][nf] = __builtin_amdgcn_mfma_f32_16x16x32_bf16(
                av[mf], bv[nf], acc[mf][nf], 0, 0, 0);
      }
    }
  }

  // epilogue: out = acc + x + conv_b   (C/D: col=lane&15, row=quad*4+reg)
  float cb[4];
#pragma unroll
  for (int nf = 0; nf < 4; ++nf)
    cb[nf] = conv_b[col0 + wn * 64 + nf * 16 + r15];
#pragma unroll
  for (int mf = 0; mf < 4; ++mf) {
#pragma unroll
    for (int rr = 0; rr < 4; ++rr) {
      int grow = row0 + wm * 64 + mf * 16 + q * 4 + rr;
      size_t base = ((size_t)grow << 9) + col0 + wn * 64 + r15;
#pragma unroll
      for (int nf = 0; nf < 4; ++nf)
        out[base + nf * 16] = acc[mf][nf][rr] + x[base + nf * 16] + cb[nf];
    }
  }
}

// ---------------------------------------------------------------------------
extern "C" void kernel_launch(void* const* d_in, const int* in_sizes, int n_in,
                              void* d_out, int out_size, void* d_ws,
                              size_t ws_size, hipStream_t stream) {
  const float* x = (const float*)d_in[0];
  const float* gamma = (const float*)d_in[1];
  const float* beta = (const float*)d_in[2];
  const float* wr = (const float*)d_in[3];
  const float* wi = (const float*)d_in[4];
  const float* conv_w = (const float*)d_in[5];
  const float* conv_b = (const float*)d_in[6];
  float* out = (float*)d_out;

  unsigned short* xs_swz = (unsigned short*)d_ws;
  float* partials = (float*)d_ws + PART_OFF_F;
  float* Y = (float*)d_ws + Y_OFF_F;
  unsigned short* wTb = (unsigned short*)d_ws + WTB_OFF_H;

  // K0: weight build + pad zero (786432+8192 elements -> 3104 blocks)
  hipLaunchKernelGGL(k_build_w, dim3(3104), dim3(256), 0, stream, conv_w, wTb,
                     xs_swz);
  hipLaunchKernelGGL(k_ln_project, dim3(Bn * NCHUNK), dim3(256), 0, stream, x,
                     gamma, beta, partials);
  hipLaunchKernelGGL(k_reduce_modes, dim3(256), dim3(256), 0, stream, partials,
                     wr, wi, Y);
  hipLaunchKernelGGL(k_synth, dim3(Bn * Sn / R3), dim3(256), 0, stream, Y,
                     xs_swz);
  hipLaunchKernelGGL(k_conv_gemm, dim3(1024), dim3(256), 0, stream, xs_swz,
                     wTb, x, conv_b, out);
}